// Round 10
// baseline (277.146 us; speedup 1.0000x reference)
//
#include <hip/hip_runtime.h>
#include <stdint.h>
#include <stddef.h>

typedef __bf16 bf16x8 __attribute__((ext_vector_type(8)));
typedef float  f32x4  __attribute__((ext_vector_type(4)));
typedef float  f32x16 __attribute__((ext_vector_type(16)));
typedef int    i32x8  __attribute__((ext_vector_type(8)));
typedef unsigned short u16;
typedef unsigned char  u8;

#define NIN   784
#define NINP  832    // 13 * 64
#define NH    1024
#define NE    512
#define ND    64
#define NOUTP 1024

#define BAR()   asm volatile("s_barrier" ::: "memory")
#define LGKM0() asm volatile("s_waitcnt lgkmcnt(0)" ::: "memory")
#define VM8()   asm volatile("s_waitcnt vmcnt(8)" ::: "memory")
#define VM6()   asm volatile("s_waitcnt vmcnt(6)" ::: "memory")
#define VM4()   asm volatile("s_waitcnt vmcnt(4)" ::: "memory")
#define VM3()   asm volatile("s_waitcnt vmcnt(3)" ::: "memory")
#define VM0()   asm volatile("s_waitcnt vmcnt(0)" ::: "memory")
#define FSWZ(r) (((r) ^ ((r) >> 2)) & 3)
#define SCL1    0x7F7F7F7F            // E8M0 x4 = 1.0 scales
#define GLDS(g, l) __builtin_amdgcn_global_load_lds((__attribute__((address_space(1))) void*)(g), (__attribute__((address_space(3))) void*)(l), 16, 0, 0)

static __device__ __forceinline__ u16 f2bf(float f) {
  union { float f; unsigned u; } v; v.f = f;
  unsigned r = v.u + 0x7fffu + ((v.u >> 16) & 1u);
  return (u16)(r >> 16);
}
static __device__ __forceinline__ float bf2f(u16 b) {
  union { unsigned u; float f; } v; v.u = ((unsigned)b) << 16; return v.f;
}
static __device__ __forceinline__ unsigned pack4fp8(float a, float b, float c, float d) {
  unsigned p;
  asm("v_cvt_pk_fp8_f32 %0, %1, %2" : "=v"(p) : "v"(a), "v"(b));
  asm("v_cvt_pk_fp8_f32 %0, %1, %2 op_sel:[0,0,1]" : "+v"(p) : "v"(c), "v"(d));
  return p;
}
static __device__ __forceinline__ u8 f2fp8(float a) {
  unsigned p;
  asm("v_cvt_pk_fp8_f32 %0, %1, %2" : "=v"(p) : "v"(a), "v"(a));
  return (u8)(p & 0xff);
}

// fp8 tiled layout: blk=(r>>8)*(Cp>>6)+(c>>6) [16384 B],
//   off = (r&255)*64 + ((((c>>4)&3)^FSWZ(r))<<4) + (c&15)
static __device__ __forceinline__ size_t t8off(int r, int c, int Cp) {
  return ((size_t)(r >> 8) * (Cp >> 6) + (c >> 6)) * 16384
       + ((r & 255) << 6) + ((((c >> 4) & 3) ^ FSWZ(r)) << 4) + (c & 15);
}

// ---------- x cast (big, stays separate) ----------
__global__ void cast_tiled8(const float* __restrict__ src, u8* __restrict__ dst,
                            int R, int C, int Cp) {
  int r = blockIdx.y;
  int c4 = (blockIdx.x * blockDim.x + threadIdx.x) * 4;
  if (c4 >= Cp) return;
  unsigned o = 0;
  if (r < R && c4 < C) {
    const float4 v = *(const float4*)&src[(size_t)r * C + c4];
    o = pack4fp8(v.x, v.y, v.z, v.w);
  }
  *(unsigned*)&dst[t8off(r, c4, Cp)] = o;
}

// ---------- all 6 weight casts in ONE launch (blockIdx.z = matrix id) ----------
__global__ void prep_weights(const float* __restrict__ We1, const float* __restrict__ We2,
                             const float* __restrict__ Wd1, const float* __restrict__ Wd2,
                             const float* __restrict__ Wd3, const float* __restrict__ We3,
                             u8* __restrict__ d0, u8* __restrict__ d1, u8* __restrict__ d2,
                             u8* __restrict__ d3, u8* __restrict__ d4, u8* __restrict__ d5) {
  int id = blockIdx.z, r = blockIdx.y;
  int c4 = threadIdx.x * 4;
  const float* src; u8* dst; int R, C, Cp; bool rm = false;
  switch (id) {
    case 0: src = We1; dst = d0; R = 1024; C = NIN;  Cp = NINP; break;
    case 1: src = We2; dst = d1; R = 1024; C = 1024; Cp = 1024; break;
    case 2: src = Wd1; dst = d2; R = 1024; C = 64;   Cp = 64;   break;
    case 3: src = Wd2; dst = d3; R = 1024; C = 1024; Cp = 1024; break;
    case 4: src = Wd3; dst = d4; R = NIN;  C = 1024; Cp = 1024; break;   // rows >= 784 zero
    default: src = We3; dst = d5; R = 64;  C = 1024; Cp = 1024; rm = true; break;
  }
  if (c4 >= Cp || (rm && r >= R)) return;
  unsigned o = 0;
  if (r < R && c4 < C) {
    const float4 v = *(const float4*)&src[(size_t)r * C + c4];
    o = pack4fp8(v.x, v.y, v.z, v.w);
  }
  if (rm) *(unsigned*)&dst[(size_t)r * Cp + c4] = o;
  else    *(unsigned*)&dst[t8off(r, c4, Cp)] = o;
}

// ---------- emb prep + zero loss accumulator & ticket ----------
__global__ void emb_prep(const float* __restrict__ emb, u16* __restrict__ ebf,
                         float* __restrict__ cvec, float* __restrict__ lossa,
                         unsigned* __restrict__ tick) {
  int j = blockIdx.x, l = threadIdx.x;
  if (j == 0 && l == 0) { lossa[0] = 0.f; tick[0] = 0u; }
  float v = emb[j * ND + l];
  ebf[j * 64 + (((l >> 3) ^ (j & 7)) << 3) + (l & 7)] = f2bf(v);
  float s = v * v;
  #pragma unroll
  for (int off = 32; off > 0; off >>= 1) s += __shfl_down(s, off);
  if (l == 0) cvec[j] = s;
}

// =========================================================================
// 128x128-tile MX-fp8 GEMM: 4 waves, 32x32x64 scaled MFMA, 3-deep prefetch,
// 2 raw barriers / K-tile, 48 KiB LDS, 3 blocks/CU.
// =========================================================================
template <int ACT, int OMODE, bool NCHK>   // OMODE: 0 f32 rm direct, 1 fp8 tiled via LDS
__global__ __launch_bounds__(256, 3)
void gemm128mx(const u8* __restrict__ A, const u8* __restrict__ Bm,
               const float* __restrict__ bias, float* __restrict__ Cf,
               u8* __restrict__ Cb, int N, int K, int ldc, int ntiles) {
  __shared__ __attribute__((aligned(128))) u8 lds[49152];  // A:3x8K | B:3x8K
  const int tid = threadIdx.x, lane = tid & 63, w = tid >> 6;
  const int wr = w >> 1, wc = w & 1;
  const int l31 = lane & 31, h = lane >> 5;

  int nwg = gridDim.x, cpx = nwg >> 3, b = blockIdx.x;
  int sb = (b & 7) * cpx + (b >> 3);
  int tm = sb / ntiles, tn = sb % ntiles;

  const int NT = K >> 6;
  const u8* Ap = A + (size_t)(tm >> 1) * NT * 16384 + (size_t)(tm & 1) * 8192;
  const u8* Bp = Bm + (size_t)(tn >> 1) * NT * 16384 + (size_t)(tn & 1) * 8192;

  auto stage = [&](int t, int buf) {
    #pragma unroll
    for (int i = 0; i < 2; ++i)
      GLDS(Ap + (size_t)t * 16384 + ((i * 256 + tid) << 4),
           lds + buf * 8192 + ((i * 256 + w * 64) << 4));
    #pragma unroll
    for (int i = 0; i < 2; ++i)
      GLDS(Bp + (size_t)t * 16384 + ((i * 256 + tid) << 4),
           lds + 24576 + buf * 8192 + ((i * 256 + w * 64) << 4));
  };

  f32x16 acc[2][2] = {};
  stage(0, 0);
  if (NT > 1) stage(1, 1);
  if (NT > 2) stage(2, 2);

  for (int t = 0; t < NT; ++t) {
    const int buf = t % 3;
    if (t + 2 < NT) { VM8(); } else if (t + 1 < NT) { VM4(); } else { VM0(); }
    BAR();
    const u8* lA = lds + buf * 8192;
    const u8* lB = lds + 24576 + buf * 8192;
    i32x8 af[2], bf_[2];
    #pragma unroll
    for (int s = 0; s < 2; ++s) {
      int row = wr * 64 + s * 32 + l31;
      int F = FSWZ(row);
      const u8* base = lA + row * 64;
      int4 lo = *(const int4*)&base[(((h << 1)    ) ^ F) << 4];
      int4 hi = *(const int4*)&base[(((h << 1) | 1) ^ F) << 4];
      af[s][0] = lo.x; af[s][1] = lo.y; af[s][2] = lo.z; af[s][3] = lo.w;
      af[s][4] = hi.x; af[s][5] = hi.y; af[s][6] = hi.z; af[s][7] = hi.w;
    }
    #pragma unroll
    for (int s = 0; s < 2; ++s) {
      int row = wc * 64 + s * 32 + l31;
      int F = FSWZ(row);
      const u8* base = lB + row * 64;
      int4 lo = *(const int4*)&base[(((h << 1)    ) ^ F) << 4];
      int4 hi = *(const int4*)&base[(((h << 1) | 1) ^ F) << 4];
      bf_[s][0] = lo.x; bf_[s][1] = lo.y; bf_[s][2] = lo.z; bf_[s][3] = lo.w;
      bf_[s][4] = hi.x; bf_[s][5] = hi.y; bf_[s][6] = hi.z; bf_[s][7] = hi.w;
    }
    LGKM0();
    BAR();
    if (t + 3 < NT) stage(t + 3, buf);
    #pragma unroll
    for (int ms = 0; ms < 2; ++ms)
      #pragma unroll
      for (int ns = 0; ns < 2; ++ns)
        acc[ms][ns] = __builtin_amdgcn_mfma_scale_f32_32x32x64_f8f6f4(
            af[ms], bf_[ns], acc[ms][ns], 0, 0, 0, SCL1, 0, SCL1);
  }

  // ---- epilogue. 32x32 C/D: col = l31, row = (r&3) + 8*(r>>2) + 4*h ----
  float bv[2];
  #pragma unroll
  for (int ns = 0; ns < 2; ++ns) {
    int col = tn * 128 + wc * 64 + ns * 32 + l31;
    bv[ns] = (!NCHK || col < N) ? bias[col] : 0.f;
  }

  if (OMODE == 0) {
    #pragma unroll
    for (int ms = 0; ms < 2; ++ms)
      #pragma unroll
      for (int r = 0; r < 16; ++r) {
        int row = tm * 128 + wr * 64 + ms * 32 + (r & 3) + ((r >> 2) << 3) + (h << 2);
        #pragma unroll
        for (int ns = 0; ns < 2; ++ns) {
          int col = tn * 128 + wc * 64 + ns * 32 + l31;
          if (NCHK && col >= N) continue;
          float v = acc[ms][ns][r] + bv[ns];
          if (ACT == 1) v = fmaxf(v, 0.f);
          if (ACT == 2) v = 1.f / (1.f + __expf(-v));
          Cf[(size_t)row * ldc + col] = v;
        }
      }
  } else {
    float* lf = (float*)lds;                 // [64][128] f32 = 32 KB
    #pragma unroll
    for (int p = 0; p < 2; ++p) {
      __syncthreads();
      if (wr == p) {
        #pragma unroll
        for (int ms = 0; ms < 2; ++ms)
          #pragma unroll
          for (int r = 0; r < 16; ++r) {
            int lrow = ms * 32 + (r & 3) + ((r >> 2) << 3) + (h << 2);  // 0..63
            #pragma unroll
            for (int ns = 0; ns < 2; ++ns) {
              int col = wc * 64 + ns * 32 + l31;                        // 0..127
              float v = acc[ms][ns][r] + bv[ns];
              if (ACT == 1) v = fmaxf(v, 0.f);
              lf[lrow * 128 + (((col >> 2) ^ (lrow & 31)) << 2) + (col & 3)] = v;
            }
          }
      }
      __syncthreads();
      #pragma unroll
      for (int it = 0; it < 2; ++it) {
        int idx = it * 256 + tid;            // 512 chunks of 16 cols
        int lrow = idx >> 3, cc = idx & 7;
        f32x4 q[4];
        #pragma unroll
        for (int s = 0; s < 4; ++s)
          q[s] = *(const f32x4*)&lf[lrow * 128 + (((cc * 4 + s) ^ (lrow & 31)) << 2)];
        int R = tm * 128 + p * 64 + lrow;
        int C = tn * 128 + cc * 16;
        int4 o;
        o.x = pack4fp8(q[0][0], q[0][1], q[0][2], q[0][3]);
        o.y = pack4fp8(q[1][0], q[1][1], q[1][2], q[1][3]);
        o.z = pack4fp8(q[2][0], q[2][1], q[2][2], q[2][3]);
        o.w = pack4fp8(q[3][0], q[3][1], q[3][2], q[3][3]);
        *(int4*)&Cb[t8off(R, C, ldc)] = o;
      }
    }
  }
}

// =========================================================================
// Fused z = hB @ We3^T + be3 ; scores ; argmin ; q gather ; loss (+finalize)
// 3-deep prefetch, raw barriers, atomic-ticket loss finalize.
// =========================================================================
__global__ __launch_bounds__(256, 1)
void z_vq(const u8* __restrict__ Atiled, const u8* __restrict__ Wrm,
          const float* __restrict__ be3, const u16* __restrict__ ebf,
          const float* __restrict__ cvec, u8* __restrict__ qb8,
          float* __restrict__ lossacc, unsigned* __restrict__ tick,
          float* __restrict__ out_loss, float denom) {
  __shared__ u8 lsA[3][128 * 64];   // 24 KB
  __shared__ u8 lsW[3][64 * 64];    // 12 KB
  __shared__ u16 embl[512 * 64];    // 64 KB
  __shared__ float zls[128 * 68];
  __shared__ int bidxl[128];

  const int t = threadIdx.x;
  const int lane = t & 63;
  const int w = t >> 6;
  const int lr = lane & 15, hi = lane >> 4;
  const int tm = blockIdx.x;

  #pragma unroll
  for (int i = 0; i < 16; ++i) {
    const u16* g = ebf + (size_t)((i * 256 + t) << 3);
    u16* l = embl + (size_t)((i * 256 + w * 64) << 3);
    GLDS(g, l);
  }

  const size_t abase0 = ((size_t)(tm >> 1) * 16) * 16384 + (size_t)(tm & 1) * 8192;
  auto stageA = [&](int kt, int buf) {
    #pragma unroll
    for (int i = 0; i < 2; ++i) {
      const u8* g = Atiled + abase0 + (size_t)kt * 16384 + ((i * 256 + t) << 4);
      u8* l = lsA[buf] + ((i * 256 + w * 64) << 4);
      GLDS(g, l);
    }
  };
  auto stageW = [&](int kt, int buf) {
    int row = w * 16 + (lane >> 2), p = lane & 3;
    const u8* g = Wrm + (size_t)row * 1024 + kt * 64 + ((p ^ FSWZ(row)) << 4);
    u8* l = lsW[buf] + ((w * 64) << 4);
    GLDS(g, l);
  };

  f32x4 acc[2][4] = {};
  stageA(0, 0); stageW(0, 0);
  stageA(1, 1); stageW(1, 1);
  stageA(2, 2); stageW(2, 2);
  for (int kt = 0; kt < 16; ++kt) {
    const int bf = kt % 3;
    if (kt < 14) { VM6(); } else if (kt == 14) { VM3(); } else { VM0(); }
    BAR();
    #pragma unroll
    for (int kk = 0; kk < 64; kk += 32) {
      long af[2], bfr[4];
      #pragma unroll
      for (int m = 0; m < 2; ++m) {
        int row = w * 32 + m * 16 + lr;
        int ch = ((kk >> 4) + (hi >> 1)) ^ FSWZ(row);
        af[m] = *(const long*)&lsA[bf][row * 64 + ch * 16 + ((hi & 1) << 3)];
      }
      #pragma unroll
      for (int n = 0; n < 4; ++n) {
        int row = n * 16 + lr;
        int ch = ((kk >> 4) + (hi >> 1)) ^ FSWZ(row);
        bfr[n] = *(const long*)&lsW[bf][row * 64 + ch * 16 + ((hi & 1) << 3)];
      }
      #pragma unroll
      for (int m = 0; m < 2; ++m)
        #pragma unroll
        for (int n = 0; n < 4; ++n)
          acc[m][n] = __builtin_amdgcn_mfma_f32_16x16x32_fp8_fp8(af[m], bfr[n], acc[m][n], 0, 0, 0);
    }
    LGKM0();
    BAR();
    if (kt + 3 < 16) { stageA(kt + 3, bf); stageW(kt + 3, bf); }
  }

  #pragma unroll
  for (int m = 0; m < 2; ++m)
    #pragma unroll
    for (int j = 0; j < 4; ++j) {
      int row = w * 32 + m * 16 + hi * 4 + j;
      #pragma unroll
      for (int n = 0; n < 4; ++n) {
        int col = n * 16 + lr;
        zls[row * 68 + col] = acc[m][n][j] + be3[col];
      }
    }
  __syncthreads();

  bf16x8 azf[2][2];
  #pragma unroll
  for (int rt = 0; rt < 2; ++rt)
    #pragma unroll
    for (int kf = 0; kf < 2; ++kf) {
      int row = w * 32 + rt * 16 + lr;
      union { bf16x8 v; u16 u[8]; } pk;
      #pragma unroll
      for (int e = 0; e < 8; ++e)
        pk.u[e] = f2bf(zls[row * 68 + kf * 32 + hi * 8 + e]);
      azf[rt][kf] = pk.v;
    }

  float bvv[2][4]; int bii[2][4];
  #pragma unroll
  for (int rt = 0; rt < 2; ++rt)
    #pragma unroll
    for (int j = 0; j < 4; ++j) { bvv[rt][j] = 3.4e38f; bii[rt][j] = 0; }

  for (int ct = 0; ct < 32; ++ct) {
    bf16x8 bqf[2];
    #pragma unroll
    for (int kf = 0; kf < 2; ++kf) {
      int row = ct * 16 + lr;
      int ch = (kf * 4 + hi) ^ (row & 7);
      bqf[kf] = *(const bf16x8*)&embl[row * 64 + ch * 8];
    }
    float cv = cvec[ct * 16 + lr];
    #pragma unroll
    for (int rt = 0; rt < 2; ++rt) {
      f32x4 sc = {};
      sc = __builtin_amdgcn_mfma_f32_16x16x32_bf16(azf[rt][0], bqf[0], sc, 0, 0, 0);
      sc = __builtin_amdgcn_mfma_f32_16x16x32_bf16(azf[rt][1], bqf[1], sc, 0, 0, 0);
      int code = ct * 16 + lr;
      #pragma unroll
      for (int j = 0; j < 4; ++j) {
        float d = cv - sc[j];
        if (d < bvv[rt][j]) { bvv[rt][j] = d; bii[rt][j] = code; }
      }
    }
  }
  #pragma unroll
  for (int off = 1; off < 16; off <<= 1) {
    #pragma unroll
    for (int rt = 0; rt < 2; ++rt)
      #pragma unroll
      for (int j = 0; j < 4; ++j) {
        float ov = __shfl_xor(bvv[rt][j], off);
        int   oi = __shfl_xor(bii[rt][j], off);
        if (ov < bvv[rt][j] || (ov == bvv[rt][j] && oi < bii[rt][j])) {
          bvv[rt][j] = ov; bii[rt][j] = oi;
        }
      }
  }
  if (lr == 0) {
    #pragma unroll
    for (int rt = 0; rt < 2; ++rt)
      #pragma unroll
      for (int j = 0; j < 4; ++j)
        bidxl[w * 32 + rt * 16 + hi * 4 + j] = bii[rt][j];
  }
  __syncthreads();

  const int gr0 = tm * 128;
  float ls = 0.f;
  #pragma unroll 4
  for (int r8 = 0; r8 < 32; ++r8) {
    int row = w * 32 + r8;
    int bi = bidxl[row];
    u16 qu = embl[bi * 64 + (((lane >> 3) ^ (bi & 7)) << 3) + (lane & 7)];
    float qf = bf2f(qu);
    float d = qf - zls[row * 68 + lane];
    ls += d * d;
    int R = gr0 + row;
    qb8[(size_t)R * 64 + ((((lane >> 4) & 3) ^ FSWZ(R)) << 4) + (lane & 15)] = f2fp8(qf);
  }
  #pragma unroll
  for (int off = 32; off > 0; off >>= 1) ls += __shfl_down(ls, off);
  if (lane == 0) atomicAdd(lossacc, ls);

  // ---- last-block finalize (device-scope atomics; tick zeroed by emb_prep) ----
  __syncthreads();
  if (t == 0) {
    __threadfence();
    unsigned tk = atomicAdd(tick, 1u);
    if (tk == gridDim.x - 1) {
      float v = atomicAdd(lossacc, 0.f);   // coherent read
      out_loss[0] = v * 1.25f / denom;
    }
  }
}

// ---------- launch ----------
extern "C" void kernel_launch(void* const* d_in, const int* in_sizes, int n_in,
                              void* d_out, int out_size, void* d_ws, size_t ws_size,
                              hipStream_t stream) {
  const float* x   = (const float*)d_in[0];
  const float* emb = (const float*)d_in[1];
  const float* We1 = (const float*)d_in[2];
  const float* be1 = (const float*)d_in[3];
  const float* We2 = (const float*)d_in[4];
  const float* be2 = (const float*)d_in[5];
  const float* We3 = (const float*)d_in[6];
  const float* be3 = (const float*)d_in[7];
  const float* Wd1 = (const float*)d_in[8];
  const float* bd1 = (const float*)d_in[9];
  const float* Wd2 = (const float*)d_in[10];
  const float* bd2 = (const float*)d_in[11];
  const float* Wd3 = (const float*)d_in[12];
  const float* bd3 = (const float*)d_in[13];

  const int Bn = in_sizes[0] / NIN;              // 32768
  float* out = (float*)d_out;
  float* out_loss = out + (size_t)Bn * NIN;

  char* ws = (char*)d_ws;
  size_t off = 0;
  auto take = [&](size_t bytes) { char* p = ws + off; off += (bytes + 255) & ~(size_t)255; return p; };

  u8*    xpad8 = (u8*)take((size_t)Bn * NINP);     // fp8 tiled
  u8*    hA8   = (u8*)take((size_t)Bn * NH);       // fp8 tiled: h1 -> h3
  u8*    hB8   = (u8*)take((size_t)Bn * NH);       // fp8 tiled: h2 -> h4
  u8*    qb8   = (u8*)take((size_t)Bn * ND);       // fp8 tiled (Cp=64)
  u8*    we1p8 = (u8*)take((size_t)NH * NINP);     // fp8 tiled
  u8*    we2b8 = (u8*)take((size_t)NH * NH);       // fp8 tiled
  u8*    we3r8 = (u8*)take((size_t)64 * NH);       // fp8 row-major
  u8*    wd1b8 = (u8*)take((size_t)NH * ND);       // fp8 tiled (Cp=64)
  u8*    wd2b8 = (u8*)take((size_t)NH * NH);       // fp8 tiled
  u8*    wd3p8 = (u8*)take((size_t)NOUTP * NH);    // fp8 tiled, rows 784+ zero
  u16*   embb  = (u16*)take((size_t)NE * ND * 2);  // bf16 rm64-swz
  float* cvec  = (float*)take(NE * 4);
  float* lossa = (float*)take(4);
  unsigned* tick = (unsigned*)take(4);

  // prep: 3 launches total
  cast_tiled8<<<dim3(1, Bn), 256, 0, stream>>>(x, xpad8, Bn, NIN, NINP);
  prep_weights<<<dim3(1, 1024, 6), 256, 0, stream>>>(We1, We2, Wd1, Wd2, Wd3, We3,
                                                     we1p8, we2b8, wd1b8, wd2b8, wd3p8, we3r8);
  emb_prep<<<NE, 64, 0, stream>>>(emb, embb, cvec, lossa, tick);

  const int mt = Bn / 128;                       // 256 row-tiles
  // encoder
  gemm128mx<1,1,false><<<mt * 8, 256, 0, stream>>>(xpad8, we1p8, be1, nullptr, hA8, NH, NINP, NH, 8);
  gemm128mx<1,1,false><<<mt * 8, 256, 0, stream>>>(hA8, we2b8, be2, nullptr, hB8, NH, NH, NH, 8);
  // fused z + VQ (+ loss finalize)
  z_vq<<<Bn / 128, 256, 0, stream>>>(hB8, we3r8, be3, embb, cvec, qb8, lossa, tick,
                                     out_loss, (float)Bn * ND);
  // decoder
  gemm128mx<1,1,false><<<mt * 8, 256, 0, stream>>>(qb8, wd1b8, bd1, nullptr, hA8, NH, 64, NH, 8);
  gemm128mx<1,1,false><<<mt * 8, 256, 0, stream>>>(hA8, wd2b8, bd2, nullptr, hB8, NH, NH, NH, 8);
  gemm128mx<2,0,true ><<<mt * 7, 256, 0, stream>>>(hB8, wd3p8, bd3, out, nullptr, NIN, NH, NIN, 7);
}

// Round 11
// 255.903 us; speedup vs baseline: 1.0830x; 1.0830x over previous
//
#include <hip/hip_runtime.h>
#include <stdint.h>
#include <stddef.h>

typedef __bf16 bf16x8 __attribute__((ext_vector_type(8)));
typedef float  f32x4  __attribute__((ext_vector_type(4)));
typedef float  f32x16 __attribute__((ext_vector_type(16)));
typedef int    i32x8  __attribute__((ext_vector_type(8)));
typedef unsigned short u16;
typedef unsigned char  u8;

#define NIN   784
#define NINP  832    // 13 * 64
#define NH    1024
#define NE    512
#define ND    64
#define NOUTP 1024

#define BAR()   asm volatile("s_barrier" ::: "memory")
#define LGKM0() asm volatile("s_waitcnt lgkmcnt(0)" ::: "memory")
#define VM4()   asm volatile("s_waitcnt vmcnt(4)" ::: "memory")
#define VM3()   asm volatile("s_waitcnt vmcnt(3)" ::: "memory")
#define VM0()   asm volatile("s_waitcnt vmcnt(0)" ::: "memory")
#define FSWZ(r) (((r) ^ ((r) >> 2)) & 3)
#define SCL1    0x7F7F7F7F            // E8M0 x4 = 1.0 scales
#define GLDS(g, l) __builtin_amdgcn_global_load_lds((__attribute__((address_space(1))) void*)(g), (__attribute__((address_space(3))) void*)(l), 16, 0, 0)

struct int4x2 { int4 a, b; };

static __device__ __forceinline__ u16 f2bf(float f) {
  union { float f; unsigned u; } v; v.f = f;
  unsigned r = v.u + 0x7fffu + ((v.u >> 16) & 1u);
  return (u16)(r >> 16);
}
static __device__ __forceinline__ float bf2f(u16 b) {
  union { unsigned u; float f; } v; v.u = ((unsigned)b) << 16; return v.f;
}
static __device__ __forceinline__ unsigned pack4fp8(float a, float b, float c, float d) {
  unsigned p;
  asm("v_cvt_pk_fp8_f32 %0, %1, %2" : "=v"(p) : "v"(a), "v"(b));
  asm("v_cvt_pk_fp8_f32 %0, %1, %2 op_sel:[0,0,1]" : "+v"(p) : "v"(c), "v"(d));
  return p;
}
static __device__ __forceinline__ u8 f2fp8(float a) {
  unsigned p;
  asm("v_cvt_pk_fp8_f32 %0, %1, %2" : "=v"(p) : "v"(a), "v"(a));
  return (u8)(p & 0xff);
}

// fp8 tiled layout: blk=(r>>8)*(Cp>>6)+(c>>6) [16384 B],
//   off = (r&255)*64 + ((((c>>4)&3)^FSWZ(r))<<4) + (c&15)
static __device__ __forceinline__ size_t t8off(int r, int c, int Cp) {
  return ((size_t)(r >> 8) * (Cp >> 6) + (c >> 6)) * 16384
       + ((r & 255) << 6) + ((((c >> 4) & 3) ^ FSWZ(r)) << 4) + (c & 15);
}

// ---------- x cast (big, stays separate) ----------
__global__ void cast_tiled8(const float* __restrict__ src, u8* __restrict__ dst,
                            int R, int C, int Cp) {
  int r = blockIdx.y;
  int c4 = (blockIdx.x * blockDim.x + threadIdx.x) * 4;
  if (c4 >= Cp) return;
  unsigned o = 0;
  if (r < R && c4 < C) {
    const float4 v = *(const float4*)&src[(size_t)r * C + c4];
    o = pack4fp8(v.x, v.y, v.z, v.w);
  }
  *(unsigned*)&dst[t8off(r, c4, Cp)] = o;
}

// ---------- all 6 weight casts in ONE launch (blockIdx.z = matrix id) ----------
__global__ void prep_weights(const float* __restrict__ We1, const float* __restrict__ We2,
                             const float* __restrict__ Wd1, const float* __restrict__ Wd2,
                             const float* __restrict__ Wd3, const float* __restrict__ We3,
                             u8* __restrict__ d0, u8* __restrict__ d1, u8* __restrict__ d2,
                             u8* __restrict__ d3, u8* __restrict__ d4, u8* __restrict__ d5) {
  int id = blockIdx.z, r = blockIdx.y;
  int c4 = threadIdx.x * 4;
  const float* src; u8* dst; int R, C, Cp; bool rm = false;
  switch (id) {
    case 0: src = We1; dst = d0; R = 1024; C = NIN;  Cp = NINP; break;
    case 1: src = We2; dst = d1; R = 1024; C = 1024; Cp = 1024; break;
    case 2: src = Wd1; dst = d2; R = 1024; C = 64;   Cp = 64;   break;
    case 3: src = Wd2; dst = d3; R = 1024; C = 1024; Cp = 1024; break;
    case 4: src = Wd3; dst = d4; R = NIN;  C = 1024; Cp = 1024; break;   // rows >= 784 zero
    default: src = We3; dst = d5; R = 64;  C = 1024; Cp = 1024; rm = true; break;
  }
  if (c4 >= Cp || (rm && r >= R)) return;
  unsigned o = 0;
  if (r < R && c4 < C) {
    const float4 v = *(const float4*)&src[(size_t)r * C + c4];
    o = pack4fp8(v.x, v.y, v.z, v.w);
  }
  if (rm) *(unsigned*)&dst[(size_t)r * Cp + c4] = o;
  else    *(unsigned*)&dst[t8off(r, c4, Cp)] = o;
}

// ---------- emb prep + zero loss accumulator & ticket ----------
__global__ void emb_prep(const float* __restrict__ emb, u16* __restrict__ ebf,
                         float* __restrict__ cvec, float* __restrict__ lossa,
                         unsigned* __restrict__ tick) {
  int j = blockIdx.x, l = threadIdx.x;
  if (j == 0 && l == 0) { lossa[0] = 0.f; tick[0] = 0u; }
  float v = emb[j * ND + l];
  ebf[j * 64 + (((l >> 3) ^ (j & 7)) << 3) + (l & 7)] = f2bf(v);
  float s = v * v;
  #pragma unroll
  for (int off = 32; off > 0; off >>= 1) s += __shfl_down(s, off);
  if (l == 0) cvec[j] = s;
}

// =========================================================================
// 128x128-tile MX-fp8 GEMM: 4 waves, 32x32x64 scaled MFMA, 2-deep prefetch,
// 2 raw barriers / K-tile, 32 KiB LDS (up to 5 blocks/CU).
// =========================================================================
template <int ACT, int OMODE, bool NCHK>   // OMODE: 0 f32 rm direct, 1 fp8 tiled via LDS
__global__ __launch_bounds__(256, 3)
void gemm128mx(const u8* __restrict__ A, const u8* __restrict__ Bm,
               const float* __restrict__ bias, float* __restrict__ Cf,
               u8* __restrict__ Cb, int N, int K, int ldc, int ntiles) {
  __shared__ __attribute__((aligned(128))) u8 lds[32768];  // A:2x8K | B:2x8K
  const int tid = threadIdx.x, lane = tid & 63, w = tid >> 6;
  const int wr = w >> 1, wc = w & 1;
  const int l31 = lane & 31, h = lane >> 5;

  int nwg = gridDim.x, cpx = nwg >> 3, b = blockIdx.x;
  int sb = (b & 7) * cpx + (b >> 3);
  int tm = sb / ntiles, tn = sb % ntiles;

  const int NT = K >> 6;
  const u8* Ap = A + (size_t)(tm >> 1) * NT * 16384 + (size_t)(tm & 1) * 8192;
  const u8* Bp = Bm + (size_t)(tn >> 1) * NT * 16384 + (size_t)(tn & 1) * 8192;

  auto stage = [&](int t, int buf) {
    #pragma unroll
    for (int i = 0; i < 2; ++i)
      GLDS(Ap + (size_t)t * 16384 + ((i * 256 + tid) << 4),
           lds + buf * 8192 + ((i * 256 + w * 64) << 4));
    #pragma unroll
    for (int i = 0; i < 2; ++i)
      GLDS(Bp + (size_t)t * 16384 + ((i * 256 + tid) << 4),
           lds + 16384 + buf * 8192 + ((i * 256 + w * 64) << 4));
  };

  f32x16 acc[2][2] = {};
  stage(0, 0);
  if (NT > 1) stage(1, 1);

  for (int t = 0; t < NT; ++t) {
    const int buf = t & 1;
    if (t + 1 < NT) { VM4(); } else { VM0(); }
    BAR();
    const u8* lA = lds + buf * 8192;
    const u8* lB = lds + 16384 + buf * 8192;
    i32x8 af[2], bf_[2];
    #pragma unroll
    for (int s = 0; s < 2; ++s) {
      int row = wr * 64 + s * 32 + l31;
      int F = FSWZ(row);
      const u8* base = lA + row * 64;
      int4 lo = *(const int4*)&base[(((h << 1)    ) ^ F) << 4];
      int4 hi = *(const int4*)&base[(((h << 1) | 1) ^ F) << 4];
      af[s] = __builtin_bit_cast(i32x8, (int4x2){lo, hi});
    }
    #pragma unroll
    for (int s = 0; s < 2; ++s) {
      int row = wc * 64 + s * 32 + l31;
      int F = FSWZ(row);
      const u8* base = lB + row * 64;
      int4 lo = *(const int4*)&base[(((h << 1)    ) ^ F) << 4];
      int4 hi = *(const int4*)&base[(((h << 1) | 1) ^ F) << 4];
      bf_[s] = __builtin_bit_cast(i32x8, (int4x2){lo, hi});
    }
    LGKM0();
    BAR();
    if (t + 2 < NT) stage(t + 2, buf);
    #pragma unroll
    for (int ms = 0; ms < 2; ++ms)
      #pragma unroll
      for (int ns = 0; ns < 2; ++ns)
        acc[ms][ns] = __builtin_amdgcn_mfma_scale_f32_32x32x64_f8f6f4(
            af[ms], bf_[ns], acc[ms][ns], 0, 0, 0, SCL1, 0, SCL1);
  }

  // ---- epilogue. 32x32 C/D: col = l31, row = (r&3) + 8*(r>>2) + 4*h ----
  float bv[2];
  #pragma unroll
  for (int ns = 0; ns < 2; ++ns) {
    int col = tn * 128 + wc * 64 + ns * 32 + l31;
    bv[ns] = (!NCHK || col < N) ? bias[col] : 0.f;
  }

  if (OMODE == 0) {
    #pragma unroll
    for (int ms = 0; ms < 2; ++ms)
      #pragma unroll
      for (int r = 0; r < 16; ++r) {
        int row = tm * 128 + wr * 64 + ms * 32 + (r & 3) + ((r >> 2) << 3) + (h << 2);
        #pragma unroll
        for (int ns = 0; ns < 2; ++ns) {
          int col = tn * 128 + wc * 64 + ns * 32 + l31;
          if (NCHK && col >= N) continue;
          float v = acc[ms][ns][r] + bv[ns];
          if (ACT == 1) v = fmaxf(v, 0.f);
          if (ACT == 2) v = 1.f / (1.f + __expf(-v));
          Cf[(size_t)row * ldc + col] = v;
        }
      }
  } else {
    float* lf = (float*)lds;                 // [64][128] f32 = 32 KB
    #pragma unroll
    for (int p = 0; p < 2; ++p) {
      __syncthreads();
      if (wr == p) {
        #pragma unroll
        for (int ms = 0; ms < 2; ++ms)
          #pragma unroll
          for (int r = 0; r < 16; ++r) {
            int lrow = ms * 32 + (r & 3) + ((r >> 2) << 3) + (h << 2);  // 0..63
            #pragma unroll
            for (int ns = 0; ns < 2; ++ns) {
              int col = wc * 64 + ns * 32 + l31;                        // 0..127
              float v = acc[ms][ns][r] + bv[ns];
              if (ACT == 1) v = fmaxf(v, 0.f);
              lf[lrow * 128 + (((col >> 2) ^ (lrow & 31)) << 2) + (col & 3)] = v;
            }
          }
      }
      __syncthreads();
      #pragma unroll
      for (int it = 0; it < 2; ++it) {
        int idx = it * 256 + tid;            // 512 chunks of 16 cols
        int lrow = idx >> 3, cc = idx & 7;
        f32x4 q[4];
        #pragma unroll
        for (int s = 0; s < 4; ++s)
          q[s] = *(const f32x4*)&lf[lrow * 128 + (((cc * 4 + s) ^ (lrow & 31)) << 2)];
        int R = tm * 128 + p * 64 + lrow;
        int C = tn * 128 + cc * 16;
        int4 o;
        o.x = pack4fp8(q[0][0], q[0][1], q[0][2], q[0][3]);
        o.y = pack4fp8(q[1][0], q[1][1], q[1][2], q[1][3]);
        o.z = pack4fp8(q[2][0], q[2][1], q[2][2], q[2][3]);
        o.w = pack4fp8(q[3][0], q[3][1], q[3][2], q[3][3]);
        *(int4*)&Cb[t8off(R, C, ldc)] = o;
      }
    }
  }
}

// =========================================================================
// Fused z = hB @ We3^T + be3 ; scores ; argmin ; q gather ; loss (+finalize)
// 2-deep prefetch, raw barriers, atomic-ticket loss finalize.
// =========================================================================
__global__ __launch_bounds__(256, 1)
void z_vq(const u8* __restrict__ Atiled, const u8* __restrict__ Wrm,
          const float* __restrict__ be3, const u16* __restrict__ ebf,
          const float* __restrict__ cvec, u8* __restrict__ qb8,
          float* __restrict__ lossacc, unsigned* __restrict__ tick,
          float* __restrict__ out_loss, float denom) {
  __shared__ u8 lsA[2][128 * 64];   // 16 KB
  __shared__ u8 lsW[2][64 * 64];    // 8 KB
  __shared__ u16 embl[512 * 64];    // 64 KB
  __shared__ float zls[128 * 68];
  __shared__ int bidxl[128];

  const int t = threadIdx.x;
  const int lane = t & 63;
  const int w = t >> 6;
  const int lr = lane & 15, hi = lane >> 4;
  const int tm = blockIdx.x;

  #pragma unroll
  for (int i = 0; i < 16; ++i) {
    const u16* g = ebf + (size_t)((i * 256 + t) << 3);
    u16* l = embl + (size_t)((i * 256 + w * 64) << 3);
    GLDS(g, l);
  }

  const size_t abase0 = ((size_t)(tm >> 1) * 16) * 16384 + (size_t)(tm & 1) * 8192;
  auto stageA = [&](int kt, int buf) {
    #pragma unroll
    for (int i = 0; i < 2; ++i) {
      const u8* g = Atiled + abase0 + (size_t)kt * 16384 + ((i * 256 + t) << 4);
      u8* l = lsA[buf] + ((i * 256 + w * 64) << 4);
      GLDS(g, l);
    }
  };
  auto stageW = [&](int kt, int buf) {
    int row = w * 16 + (lane >> 2), p = lane & 3;
    const u8* g = Wrm + (size_t)row * 1024 + kt * 64 + ((p ^ FSWZ(row)) << 4);
    u8* l = lsW[buf] + ((w * 64) << 4);
    GLDS(g, l);
  };

  f32x4 acc[2][4] = {};
  stageA(0, 0); stageW(0, 0);
  stageA(1, 1); stageW(1, 1);
  for (int kt = 0; kt < 16; ++kt) {
    const int bf = kt & 1;
    if (kt < 15) { VM3(); } else { VM0(); }
    BAR();
    #pragma unroll
    for (int kk = 0; kk < 64; kk += 32) {
      long af[2], bfr[4];
      #pragma unroll
      for (int m = 0; m < 2; ++m) {
        int row = w * 32 + m * 16 + lr;
        int ch = ((kk >> 4) + (hi >> 1)) ^ FSWZ(row);
        af[m] = *(const long*)&lsA[bf][row * 64 + ch * 16 + ((hi & 1) << 3)];
      }
      #pragma unroll
      for (int n = 0; n < 4; ++n) {
        int row = n * 16 + lr;
        int ch = ((kk >> 4) + (hi >> 1)) ^ FSWZ(row);
        bfr[n] = *(const long*)&lsW[bf][row * 64 + ch * 16 + ((hi & 1) << 3)];
      }
      #pragma unroll
      for (int m = 0; m < 2; ++m)
        #pragma unroll
        for (int n = 0; n < 4; ++n)
          acc[m][n] = __builtin_amdgcn_mfma_f32_16x16x32_fp8_fp8(af[m], bfr[n], acc[m][n], 0, 0, 0);
    }
    LGKM0();
    BAR();
    if (kt + 2 < 16) { stageA(kt + 2, bf); stageW(kt + 2, bf); }
  }

  #pragma unroll
  for (int m = 0; m < 2; ++m)
    #pragma unroll
    for (int j = 0; j < 4; ++j) {
      int row = w * 32 + m * 16 + hi * 4 + j;
      #pragma unroll
      for (int n = 0; n < 4; ++n) {
        int col = n * 16 + lr;
        zls[row * 68 + col] = acc[m][n][j] + be3[col];
      }
    }
  __syncthreads();

  bf16x8 azf[2][2];
  #pragma unroll
  for (int rt = 0; rt < 2; ++rt)
    #pragma unroll
    for (int kf = 0; kf < 2; ++kf) {
      int row = w * 32 + rt * 16 + lr;
      union { bf16x8 v; u16 u[8]; } pk;
      #pragma unroll
      for (int e = 0; e < 8; ++e)
        pk.u[e] = f2bf(zls[row * 68 + kf * 32 + hi * 8 + e]);
      azf[rt][kf] = pk.v;
    }

  float bvv[2][4]; int bii[2][4];
  #pragma unroll
  for (int rt = 0; rt < 2; ++rt)
    #pragma unroll
    for (int j = 0; j < 4; ++j) { bvv[rt][j] = 3.4e38f; bii[rt][j] = 0; }

  for (int ct = 0; ct < 32; ++ct) {
    bf16x8 bqf[2];
    #pragma unroll
    for (int kf = 0; kf < 2; ++kf) {
      int row = ct * 16 + lr;
      int ch = (kf * 4 + hi) ^ (row & 7);
      bqf[kf] = *(const bf16x8*)&embl[row * 64 + ch * 8];
    }
    float cv = cvec[ct * 16 + lr];
    #pragma unroll
    for (int rt = 0; rt < 2; ++rt) {
      f32x4 sc = {};
      sc = __builtin_amdgcn_mfma_f32_16x16x32_bf16(azf[rt][0], bqf[0], sc, 0, 0, 0);
      sc = __builtin_amdgcn_mfma_f32_16x16x32_bf16(azf[rt][1], bqf[1], sc, 0, 0, 0);
      int code = ct * 16 + lr;
      #pragma unroll
      for (int j = 0; j < 4; ++j) {
        float d = cv - sc[j];
        if (d < bvv[rt][j]) { bvv[rt][j] = d; bii[rt][j] = code; }
      }
    }
  }
  #pragma unroll
  for (int off = 1; off < 16; off <<= 1) {
    #pragma unroll
    for (int rt = 0; rt < 2; ++rt)
      #pragma unroll
      for (int j = 0; j < 4; ++j) {
        float ov = __shfl_xor(bvv[rt][j], off);
        int   oi = __shfl_xor(bii[rt][j], off);
        if (ov < bvv[rt][j] || (ov == bvv[rt][j] && oi < bii[rt][j])) {
          bvv[rt][j] = ov; bii[rt][j] = oi;
        }
      }
  }
  if (lr == 0) {
    #pragma unroll
    for (int rt = 0; rt < 2; ++rt)
      #pragma unroll
      for (int j = 0; j < 4; ++j)
        bidxl[w * 32 + rt * 16 + hi * 4 + j] = bii[rt][j];
  }
  __syncthreads();

  const int gr0 = tm * 128;
  float ls = 0.f;
  #pragma unroll 4
  for (int r8 = 0; r8 < 32; ++r8) {
    int row = w * 32 + r8;
    int bi = bidxl[row];
    u16 qu = embl[bi * 64 + (((lane >> 3) ^ (bi & 7)) << 3) + (lane & 7)];
    float qf = bf2f(qu);
    float d = qf - zls[row * 68 + lane];
    ls += d * d;
    int R = gr0 + row;
    qb8[(size_t)R * 64 + ((((lane >> 4) & 3) ^ FSWZ(R)) << 4) + (lane & 15)] = f2fp8(qf);
  }
  #pragma unroll
  for (int off = 32; off > 0; off >>= 1) ls += __shfl_down(ls, off);
  if (lane == 0) atomicAdd(lossacc, ls);

  // ---- last-block finalize (device-scope atomics; tick zeroed by emb_prep) ----
  __syncthreads();
  if (t == 0) {
    __threadfence();
    unsigned tk = atomicAdd(tick, 1u);
    if (tk == gridDim.x - 1) {
      float v = atomicAdd(lossacc, 0.f);   // coherent read
      out_loss[0] = v * 1.25f / denom;
    }
  }
}

// ---------- launch ----------
extern "C" void kernel_launch(void* const* d_in, const int* in_sizes, int n_in,
                              void* d_out, int out_size, void* d_ws, size_t ws_size,
                              hipStream_t stream) {
  const float* x   = (const float*)d_in[0];
  const float* emb = (const float*)d_in[1];
  const float* We1 = (const float*)d_in[2];
  const float* be1 = (const float*)d_in[3];
  const float* We2 = (const float*)d_in[4];
  const float* be2 = (const float*)d_in[5];
  const float* We3 = (const float*)d_in[6];
  const float* be3 = (const float*)d_in[7];
  const float* Wd1 = (const float*)d_in[8];
  const float* bd1 = (const float*)d_in[9];
  const float* Wd2 = (const float*)d_in[10];
  const float* bd2 = (const float*)d_in[11];
  const float* Wd3 = (const float*)d_in[12];
  const float* bd3 = (const float*)d_in[13];

  const int Bn = in_sizes[0] / NIN;              // 32768
  float* out = (float*)d_out;
  float* out_loss = out + (size_t)Bn * NIN;

  char* ws = (char*)d_ws;
  size_t off = 0;
  auto take = [&](size_t bytes) { char* p = ws + off; off += (bytes + 255) & ~(size_t)255; return p; };

  u8*    xpad8 = (u8*)take((size_t)Bn * NINP);     // fp8 tiled
  u8*    hA8   = (u8*)take((size_t)Bn * NH);       // fp8 tiled: h1 -> h3
  u8*    hB8   = (u8*)take((size_t)Bn * NH);       // fp8 tiled: h2 -> h4
  u8*    qb8   = (u8*)take((size_t)Bn * ND);       // fp8 tiled (Cp=64)
  u8*    we1p8 = (u8*)take((size_t)NH * NINP);     // fp8 tiled
  u8*    we2b8 = (u8*)take((size_t)NH * NH);       // fp8 tiled
  u8*    we3r8 = (u8*)take((size_t)64 * NH);       // fp8 row-major
  u8*    wd1b8 = (u8*)take((size_t)NH * ND);       // fp8 tiled (Cp=64)
  u8*    wd2b8 = (u8*)take((size_t)NH * NH);       // fp8 tiled
  u8*    wd3p8 = (u8*)take((size_t)NOUTP * NH);    // fp8 tiled, rows 784+ zero
  u16*   embb  = (u16*)take((size_t)NE * ND * 2);  // bf16 rm64-swz
  float* cvec  = (float*)take(NE * 4);
  float* lossa = (float*)take(4);
  unsigned* tick = (unsigned*)take(4);

  // prep: 3 launches total
  cast_tiled8<<<dim3(1, Bn), 256, 0, stream>>>(x, xpad8, Bn, NIN, NINP);
  prep_weights<<<dim3(1, 1024, 6), 256, 0, stream>>>(We1, We2, Wd1, Wd2, Wd3, We3,
                                                     we1p8, we2b8, wd1b8, wd2b8, wd3p8, we3r8);
  emb_prep<<<NE, 64, 0, stream>>>(emb, embb, cvec, lossa, tick);

  const int mt = Bn / 128;                       // 256 row-tiles
  // encoder
  gemm128mx<1,1,false><<<mt * 8, 256, 0, stream>>>(xpad8, we1p8, be1, nullptr, hA8, NH, NINP, NH, 8);
  gemm128mx<1,1,false><<<mt * 8, 256, 0, stream>>>(hA8, we2b8, be2, nullptr, hB8, NH, NH, NH, 8);
  // fused z + VQ (+ loss finalize)
  z_vq<<<Bn / 128, 256, 0, stream>>>(hB8, we3r8, be3, embb, cvec, qb8, lossa, tick,
                                     out_loss, (float)Bn * ND);
  // decoder
  gemm128mx<1,1,false><<<mt * 8, 256, 0, stream>>>(qb8, wd1b8, bd1, nullptr, hA8, NH, 64, NH, 8);
  gemm128mx<1,1,false><<<mt * 8, 256, 0, stream>>>(hA8, wd2b8, bd2, nullptr, hB8, NH, NH, NH, 8);
  gemm128mx<2,0,true ><<<mt * 7, 256, 0, stream>>>(hB8, wd3p8, bd3, out, nullptr, NIN, NH, NIN, 7);
}